// Round 7
// baseline (748.239 us; speedup 1.0000x reference)
//
#include <hip/hip_runtime.h>
#include <math.h>

#define C 256
#define S 16
#define CR 64
#define NREP 16        // psum replicas (atomic contention /16)

typedef float f4 __attribute__((ext_vector_type(4)));   // native vec: ok for nt builtins

// ---------------- Kernel 0: histogram of idx (counts per segment) ------------
__global__ __launch_bounds__(256) void k_hist(
    const int* __restrict__ idx, int* __restrict__ pcnt, int nrows)
{
    const int lane = threadIdx.x & 63;
    const int tid  = blockIdx.x * blockDim.x + threadIdx.x;
    const int T    = gridDim.x * blockDim.x;
    const int padded = ((nrows + 63) >> 6) << 6;

    int c0=0,c1=0,c2=0,c3=0,c4=0,c5=0,c6=0,c7=0,
        c8=0,c9=0,c10=0,c11=0,c12=0,c13=0,c14=0,c15=0;

    for (int i = tid; i < padded; i += T) {
        const int v = (i < nrows) ? idx[i] : -1;
        #define CNT(K) c##K += (int)__popcll(__ballot(v == K));
        CNT(0)  CNT(1)  CNT(2)  CNT(3)  CNT(4)  CNT(5)  CNT(6)  CNT(7)
        CNT(8)  CNT(9)  CNT(10) CNT(11) CNT(12) CNT(13) CNT(14) CNT(15)
        #undef CNT
    }
    if (lane == 0) {
        #define FL(K) if (c##K) atomicAdd(&pcnt[K], c##K);
        FL(0)  FL(1)  FL(2)  FL(3)  FL(4)  FL(5)  FL(6)  FL(7)
        FL(8)  FL(9)  FL(10) FL(11) FL(12) FL(13) FL(14) FL(15)
        #undef FL
    }
}

// ---------------- Kernel 1: segment sums, predicated FMAC --------------------
// One wave per 64-row superblock; lane owns channels 4l..4l+3 (16 B/lane).
// idx fetched coalesced once per superblock (readlane per row). 8 rows'
// nt-loads in flight per batch. Accumulator select is arithmetic (scalar
// cselect mask + fma) -> straight-line, no branches, no LDS in hot loop.
// Flush: 32 KB LDS reduction in two 8-segment chunks (4 blocks/CU resident).
__global__ __launch_bounds__(256, 4) void k_segsum(
    const float* __restrict__ x, const int* __restrict__ idx,
    float* __restrict__ psum, int nrows)
{
    const int lane = threadIdx.x & 63;
    const int w    = threadIdx.x >> 6;
    const int gw   = blockIdx.x * 4 + w;
    const int nw   = gridDim.x * 4;

    f4 a0={0,0,0,0},a1={0,0,0,0},a2={0,0,0,0},a3={0,0,0,0},
       a4={0,0,0,0},a5={0,0,0,0},a6={0,0,0,0},a7={0,0,0,0},
       a8={0,0,0,0},a9={0,0,0,0},a10={0,0,0,0},a11={0,0,0,0},
       a12={0,0,0,0},a13={0,0,0,0},a14={0,0,0,0},a15={0,0,0,0};

    const f4* __restrict__ x4 = reinterpret_cast<const f4*>(x);

    #define ACC1(K, sv, vv) { const float m = (sv == K) ? 1.0f : 0.0f; \
        a##K.x = fmaf(m, vv.x, a##K.x); a##K.y = fmaf(m, vv.y, a##K.y); \
        a##K.z = fmaf(m, vv.z, a##K.z); a##K.w = fmaf(m, vv.w, a##K.w); }
    #define ROW(sv, vv) \
        ACC1(0,sv,vv)  ACC1(1,sv,vv)  ACC1(2,sv,vv)  ACC1(3,sv,vv) \
        ACC1(4,sv,vv)  ACC1(5,sv,vv)  ACC1(6,sv,vv)  ACC1(7,sv,vv) \
        ACC1(8,sv,vv)  ACC1(9,sv,vv)  ACC1(10,sv,vv) ACC1(11,sv,vv) \
        ACC1(12,sv,vv) ACC1(13,sv,vv) ACC1(14,sv,vv) ACC1(15,sv,vv)

    const int nsb = nrows >> 6;
    for (int sb = gw; sb < nsb; sb += nw) {
        const int row0 = sb << 6;
        const int vidx = idx[row0 + lane];             // 64 indices, coalesced
        const f4* __restrict__ p = x4 + (size_t)row0 * (C/4) + lane;
        #pragma unroll 1
        for (int j = 0; j < 64; j += 8) {
            f4  v[8];
            int s[8];
            #pragma unroll
            for (int k = 0; k < 8; k++)                // 8 KB in flight (nt)
                v[k] = __builtin_nontemporal_load(&p[(size_t)(j + k) * (C/4)]);
            #pragma unroll
            for (int k = 0; k < 8; k++)
                s[k] = __builtin_amdgcn_readlane(vidx, j + k);
            #pragma unroll
            for (int k = 0; k < 8; k++) { ROW(s[k], v[k]) }
        }
    }
    if (gw == 0) {                                     // tail (none if %64==0)
        for (int r = nsb << 6; r < nrows; ++r) {
            const int sv = __builtin_amdgcn_readfirstlane(idx[r]);
            const f4 vv = x4[(size_t)r * (C/4) + lane];
            ROW(sv, vv)
        }
    }
    #undef ROW
    #undef ACC1

    // flush: 32 KB LDS, two 8-segment chunks -> one atomic/elem/block
    __shared__ float red[4][8][C];
    const int t   = threadIdx.x;
    const int rep = blockIdx.x & (NREP - 1);
    float* gs = psum + (size_t)rep * S * C;

    #define ST(K, SL) *reinterpret_cast<f4*>(&red[w][SL][4 * lane]) = a##K;
    ST(0,0) ST(1,1) ST(2,2) ST(3,3) ST(4,4) ST(5,5) ST(6,6) ST(7,7)
    __syncthreads();
    #pragma unroll
    for (int s_ = 0; s_ < 8; s_++) {
        const float v = red[0][s_][t] + red[1][s_][t] +
                        red[2][s_][t] + red[3][s_][t];
        atomicAdd(&gs[s_ * C + t], v);
    }
    __syncthreads();
    ST(8,0) ST(9,1) ST(10,2) ST(11,3) ST(12,4) ST(13,5) ST(14,6) ST(15,7)
    __syncthreads();
    #pragma unroll
    for (int s_ = 0; s_ < 8; s_++) {
        const float v = red[0][s_][t] + red[1][s_][t] +
                        red[2][s_][t] + red[3][s_][t];
        atomicAdd(&gs[(8 + s_) * C + t], v);
    }
    #undef ST
}

// ---------------- Kernel 2: reduce replicas + tiny SE MLP ----------------
__global__ __launch_bounds__(256) void k_mlp(
    const float* __restrict__ psum, const int* __restrict__ pcnt,
    const float* __restrict__ w1, const float* __restrict__ w2,
    float* __restrict__ gate)
{
    __shared__ float sm[S][C];
    __shared__ float h[S][CR];
    __shared__ float cnt[S];
    const int t = threadIdx.x;

    if (t < S) cnt[t] = fmaxf((float)pcnt[t], 1.0f);
    __syncthreads();

    for (int i = t; i < S * C; i += 256) {
        float v = 0.0f;
        #pragma unroll
        for (int r = 0; r < NREP; r++) v += psum[r * S * C + i];
        sm[i / C][i % C] = v / cnt[i / C];
    }
    __syncthreads();

    for (int o = t; o < S * CR; o += 256) {
        const int s = o / CR, j = o % CR;
        float acc = 0.0f;
        #pragma unroll 4
        for (int k = 0; k < C; k++) acc += sm[s][k] * w1[k * CR + j];
        h[s][j] = fmaxf(acc, 0.0f);
    }
    __syncthreads();

    for (int o = t; o < S * C; o += 256) {
        const int s = o / C, j = o % C;
        float acc = 0.0f;
        #pragma unroll
        for (int k = 0; k < CR; k++) acc += h[s][k] * w2[k * C + j];
        gate[o] = 1.0f / (1.0f + expf(-acc));
    }
}

// ---------------- Kernel 3: out = x * gate[idx], superblock-batched ----------
// Coalesced idx prefetch per 64-row superblock kills the idx->gate dependent
// chain; 4 consecutive rows in flight per iteration; nt on x/out streams.
__global__ __launch_bounds__(256) void k_mod(
    const float* __restrict__ x, const int* __restrict__ idx,
    const float* __restrict__ gate, float* __restrict__ out, int nrows)
{
    const int lane = threadIdx.x & 63;
    const int w    = threadIdx.x >> 6;
    const int gw   = blockIdx.x * 4 + w;
    const int nw   = gridDim.x * 4;
    const f4* __restrict__ x4 = reinterpret_cast<const f4*>(x);
    const f4* __restrict__ g4 = reinterpret_cast<const f4*>(gate);
    f4* __restrict__ o4 = reinterpret_cast<f4*>(out);

    const int nsb = nrows >> 6;
    for (int sb = gw; sb < nsb; sb += nw) {
        const int row0 = sb << 6;
        const int vidx = idx[row0 + lane];             // coalesced prefetch
        const f4* __restrict__ p = x4 + (size_t)row0 * (C/4) + lane;
        f4* __restrict__ q = o4 + (size_t)row0 * (C/4) + lane;
        #pragma unroll 1
        for (int j = 0; j < 64; j += 4) {
            const int s0 = __builtin_amdgcn_readlane(vidx, j + 0);
            const int s1 = __builtin_amdgcn_readlane(vidx, j + 1);
            const int s2 = __builtin_amdgcn_readlane(vidx, j + 2);
            const int s3 = __builtin_amdgcn_readlane(vidx, j + 3);
            f4 v0 = __builtin_nontemporal_load(&p[(size_t)(j+0) * (C/4)]);
            f4 v1 = __builtin_nontemporal_load(&p[(size_t)(j+1) * (C/4)]);
            f4 v2 = __builtin_nontemporal_load(&p[(size_t)(j+2) * (C/4)]);
            f4 v3 = __builtin_nontemporal_load(&p[(size_t)(j+3) * (C/4)]);
            const f4 g0 = g4[s0 * (C/4) + lane];       // L1-resident
            const f4 g1 = g4[s1 * (C/4) + lane];
            const f4 g2 = g4[s2 * (C/4) + lane];
            const f4 g3 = g4[s3 * (C/4) + lane];
            v0 *= g0; v1 *= g1; v2 *= g2; v3 *= g3;
            __builtin_nontemporal_store(v0, &q[(size_t)(j+0) * (C/4)]);
            __builtin_nontemporal_store(v1, &q[(size_t)(j+1) * (C/4)]);
            __builtin_nontemporal_store(v2, &q[(size_t)(j+2) * (C/4)]);
            __builtin_nontemporal_store(v3, &q[(size_t)(j+3) * (C/4)]);
        }
    }
    if (gw == 0) {                                     // tail (none if %64==0)
        for (int r = nsb << 6; r < nrows; ++r) {
            const int s = idx[r];
            f4 v = x4[(size_t)r * (C/4) + lane];
            const f4 g = g4[s * (C/4) + lane];
            v *= g;
            o4[(size_t)r * (C/4) + lane] = v;
        }
    }
}

extern "C" void kernel_launch(void* const* d_in, const int* in_sizes, int n_in,
                              void* d_out, int out_size, void* d_ws, size_t ws_size,
                              hipStream_t stream)
{
    const float* x   = (const float*)d_in[0];
    const int*   idx = (const int*)  d_in[1];
    const float* w1  = (const float*)d_in[2];
    const float* w2  = (const float*)d_in[3];
    float* out = (float*)d_out;
    const int nrows = in_sizes[1];

    // ws: [psum: NREP*S*C f32][pcnt: S i32][gate: S*C f32]
    float* psum = (float*)d_ws;
    int*   pcnt = (int*)(psum + NREP * S * C);
    float* gate = (float*)(pcnt + S);

    const size_t zero_bytes = NREP * S * C * sizeof(float) + S * sizeof(int);
    (void)hipMemsetAsync(d_ws, 0, zero_bytes, stream);

    k_hist  <<< 128, 256, 0, stream>>>(idx, pcnt, nrows);
    k_segsum<<<1024, 256, 0, stream>>>(x, idx, psum, nrows);
    k_mlp   <<<   1, 256, 0, stream>>>(psum, pcnt, w1, w2, gate);
    k_mod   <<<2048, 256, 0, stream>>>(x, idx, gate, out, nrows);
}